// Round 8
// baseline (1329.485 us; speedup 1.0000x reference)
//
#include <hip/hip_runtime.h>
#include <hip/hip_bf16.h>

// GNN: 3x GCNConv (25->64->64->32) + global mean pool (256 graphs) + MLP head.
// Round 7: chunk-grouped CSR gather. R7 counters showed the gather pinned at
// ~3.8 TB/s regardless of ILP: random-line L2-miss throughput is the limiter
// (h=25.6MB uniformly random >> 4MB per-XCD L2). Fix: counting-sort key
// widened to (dst_low, src>>14) so each row's edges are grouped by 16K-node
// src chunks (4.2MB of h = one L2); gather runs 8 passes, all blocks
// co-resident (KN=16 nodes/wave in registers), so in pass p every XCD reads
// only chunk p -> L2-resident. h-FETCH floor = 8 XCD x 25.6MB = 205MB vs
// 542MB measured flat. rpc[9][N] per-(node,chunk) pointers avoid compare
// chains. Assumes N <= 131072 (17-bit src packing).

#define IN_DIM 25
#define HID 64
#define OUT3 32
#define BK_LOG 7
#define BK_NODES 128
#define MAXB 1024
#define EPB1 16384
#define BCAP 8192
#define NCH 8            // src chunks (chunk = 16384 nodes)
#define NKEY 1024        // 128 dst-low * 8 chunks
#define KN 16            // nodes held in registers per wave-slot

__device__ inline int ld_nt_i32(const int* p) {
    return __builtin_nontemporal_load(p);
}

// ---------------- stage 1: bucket histogram (LDS-privatized) ----------------
__global__ __launch_bounds__(256) void bucket_hist(const int* __restrict__ dst,
                                                   int* __restrict__ bhist, int nE) {
    __shared__ int h[MAXB];
    for (int i = threadIdx.x; i < MAXB; i += 256) h[i] = 0;
    __syncthreads();
    int e0 = blockIdx.x * 8192;
    int cnt = min(8192, nE - e0);
    for (int i = threadIdx.x; i < cnt; i += 256)
        atomicAdd(&h[(unsigned)dst[e0 + i] >> BK_LOG], 1);
    __syncthreads();
    for (int i = threadIdx.x; i < MAXB; i += 256)
        if (h[i]) atomicAdd(&bhist[i], h[i]);
}

// ---------------- stage 2: scan bucket counts (1 block) ----------------
__global__ __launch_bounds__(256) void bucket_scan(const int* __restrict__ bhist,
                                                   int* __restrict__ bbase,
                                                   int* __restrict__ cursor,
                                                   int nb, int nE) {
    __shared__ int s4[256];
    int t = threadIdx.x;
    int v[4]; int sum = 0;
#pragma unroll
    for (int j = 0; j < 4; ++j) {
        int b = 4 * t + j;
        v[j] = (b < nb) ? bhist[b] : 0;
        sum += v[j];
    }
    s4[t] = sum;
    __syncthreads();
    for (int off = 1; off < 256; off <<= 1) {
        int mine = s4[t];
        int add = (t >= off) ? s4[t - off] : 0;
        __syncthreads();
        s4[t] = mine + add;
        __syncthreads();
    }
    int run = s4[t] - sum;
#pragma unroll
    for (int j = 0; j < 4; ++j) {
        int b = 4 * t + j;
        if (b < nb) { bbase[b] = run; cursor[b] = run; }
        run += v[j];
    }
    if (t == 0) bbase[nb] = nE;
}

// ---------------- stage 3: partition edges into buckets (coalesced) --------
__global__ __launch_bounds__(256) void partition_kernel(
        const int* __restrict__ src, const int* __restrict__ dst,
        int* __restrict__ cursor, unsigned int* __restrict__ ebuf, int nE) {
    __shared__ int lh[MAXB];
    __shared__ int lrun[MAXB];
    __shared__ int lcur[MAXB];
    __shared__ int swp[256];
    __shared__ unsigned int stg[EPB1];
    __shared__ unsigned short sbk[EPB1];
    int t = threadIdx.x;
    int e0 = blockIdx.x * EPB1;
    int cnt = min(EPB1, nE - e0);
    for (int i = t; i < MAXB; i += 256) lh[i] = 0;
    __syncthreads();
    for (int i = t; i < cnt; i += 256)
        atomicAdd(&lh[(unsigned)dst[e0 + i] >> BK_LOG], 1);
    __syncthreads();
    int v[4]; int sum = 0;
#pragma unroll
    for (int j = 0; j < 4; ++j) { v[j] = lh[4 * t + j]; sum += v[j]; }
    swp[t] = sum;
    __syncthreads();
    for (int off = 1; off < 256; off <<= 1) {
        int mine = swp[t];
        int add = (t >= off) ? swp[t - off] : 0;
        __syncthreads();
        swp[t] = mine + add;
        __syncthreads();
    }
    int run = swp[t] - sum;
#pragma unroll
    for (int j = 0; j < 4; ++j) {
        int b = 4 * t + j;
        lh[b] = run;
        lcur[b] = 0;
        if (v[j] > 0) lrun[b] = atomicAdd(&cursor[b], v[j]);
        run += v[j];
    }
    __syncthreads();
    for (int i = t; i < cnt; i += 256) {
        int d = dst[e0 + i];
        int s = src[e0 + i];
        int b = (unsigned)d >> BK_LOG;
        int lp = atomicAdd(&lcur[b], 1);
        int slot = lh[b] + lp;
        stg[slot] = ((unsigned)(d & (BK_NODES - 1)) << 17) | (unsigned)s;
        sbk[slot] = (unsigned short)b;
    }
    __syncthreads();
    for (int i = t; i < cnt; i += 256) {
        int b = sbk[i];
        int g = lrun[b] + (i - lh[b]);
        ebuf[g] = stg[i];
    }
}

// ---------------- stage 4: per-bucket sort by (dst_low, src_chunk) ---------
// key = packed_word >> 14  (top 7 bits = dst_low, next 3 = src>>14).
// Emits rpc[p][node] (p=0..8): start of node's chunk-p edge run; rpc[8] = row
// end. Also dinv[node].
__global__ __launch_bounds__(256) void bucket_csr_kernel(
        unsigned int* __restrict__ ebuf, const int* __restrict__ bbase,
        float* __restrict__ dinv, int* __restrict__ rpc, int nN) {
    int b = blockIdx.x;
    int node_lo = b << BK_LOG;
    int nn = min(BK_NODES, nN - node_lo);
    int base = bbase[b];
    int cnt = bbase[b + 1] - base;
    if (cnt > BCAP) cnt = BCAP;
    __shared__ unsigned int in[BCAP];    // 32KB
    __shared__ unsigned int outb[BCAP];  // 32KB
    __shared__ int h2[NKEY], sc2[NKEY], lc2[NKEY];   // 12KB
    int t = threadIdx.x;
    for (int i = t; i < cnt; i += 256) in[i] = ebuf[base + i];
    for (int i = t; i < NKEY; i += 256) { h2[i] = 0; lc2[i] = 0; }
    __syncthreads();
    for (int i = t; i < cnt; i += 256) atomicAdd(&h2[in[i] >> 14], 1);
    __syncthreads();
    // hierarchical inclusive scan over 1024 keys (4/thread)
    __shared__ int swp[256];
    int v[4]; int sum = 0;
#pragma unroll
    for (int j = 0; j < 4; ++j) { v[j] = h2[4 * t + j]; sum += v[j]; }
    swp[t] = sum;
    __syncthreads();
    for (int off = 1; off < 256; off <<= 1) {
        int mine = swp[t];
        int add = (t >= off) ? swp[t - off] : 0;
        __syncthreads();
        swp[t] = mine + add;
        __syncthreads();
    }
    int run = swp[t] - sum;
#pragma unroll
    for (int j = 0; j < 4; ++j) {
        run += v[j];
        sc2[4 * t + j] = run;     // inclusive
    }
    __syncthreads();
    // rpc + dinv  (E(k) = sc2[k]-h2[k] = exclusive; E(NKEY) = cnt)
    if (t < BK_NODES && t < nn) {
        int k0 = t * NCH;
        int e0 = sc2[k0] - h2[k0];
#pragma unroll
        for (int p = 0; p < NCH; ++p) {
            int kp = k0 + p;
            rpc[(size_t)p * nN + node_lo + t] = base + (sc2[kp] - h2[kp]);
        }
        int eEnd = (k0 + NCH < NKEY) ? (sc2[k0 + NCH] - h2[k0 + NCH]) : cnt;
        rpc[(size_t)NCH * nN + node_lo + t] = base + eEnd;
        dinv[node_lo + t] = rsqrtf((float)(eEnd - e0) + 1.0f);
    }
    __syncthreads();
    for (int i = t; i < cnt; i += 256) {
        unsigned int w = in[i];
        int key = w >> 14;
        int lp = atomicAdd(&lc2[key], 1);
        outb[(sc2[key] - h2[key]) + lp] = w & 0x1FFFFu;
    }
    __syncthreads();
    for (int i = t; i < cnt; i += 256) ebuf[base + i] = outb[i];
}

// ---------------- pad + pre-scale helpers ----------------
__global__ void padx_kernel(const float* __restrict__ x, const float* __restrict__ dinv,
                            float* __restrict__ xp, int n) {
    int i = blockIdx.x * 256 + threadIdx.x;
    if (i < n * 32) {
        int node = i >> 5, c = i & 31;
        xp[i] = (c < IN_DIM) ? x[(size_t)node * IN_DIM + c] * dinv[node] : 0.f;
    }
}

__global__ void padw_kernel(const float* __restrict__ W1, float* __restrict__ W1p) {
    int i = blockIdx.x * 256 + threadIdx.x;
    if (i < 32 * HID) {
        int r = i >> 6, c = i & 63;
        W1p[i] = (r < IN_DIM) ? W1[r * HID + c] : 0.f;
    }
}

// ---------------- dense layer: out = in @ W [*dinv] [+bias,relu] -----------
template<int INF, int OUTF, bool ACT, bool SCALE>
__global__ __launch_bounds__(256) void gemm_kernel(
        const float* __restrict__ in, const float* __restrict__ W,
        const float* __restrict__ bias, const float* __restrict__ dinv,
        float* __restrict__ out, int n) {
    constexpr int TPN = OUTF / 4;
    constexpr int NPB = 256 / TPN;
    constexpr int LDK = INF + 4;
    __shared__ float sW[INF * OUTF];
    __shared__ float sIn[NPB][LDK];
    for (int i = threadIdx.x; i < INF * OUTF; i += 256) sW[i] = W[i];
    int node0 = blockIdx.x * NPB;
    for (int i = threadIdx.x; i < NPB * INF; i += 256) {
        int ln = i / INF, k = i % INF;
        int node = node0 + ln;
        sIn[ln][k] = (node < n) ? in[(size_t)node * INF + k] : 0.f;
    }
    __syncthreads();
    int g   = threadIdx.x / TPN;
    int of0 = (threadIdx.x % TPN) * 4;
    int node = node0 + g;
    float4 acc = make_float4(0.f, 0.f, 0.f, 0.f);
#pragma unroll
    for (int k = 0; k < INF; ++k) {
        float aj = sIn[g][k];
        const float4 wv = *(const float4*)&sW[k * OUTF + of0];
        acc.x += aj * wv.x; acc.y += aj * wv.y;
        acc.z += aj * wv.z; acc.w += aj * wv.w;
    }
    if (ACT) {
        const float4 bv = *(const float4*)&bias[of0];
        acc.x = fmaxf(acc.x + bv.x, 0.f);
        acc.y = fmaxf(acc.y + bv.y, 0.f);
        acc.z = fmaxf(acc.z + bv.z, 0.f);
        acc.w = fmaxf(acc.w + bv.w, 0.f);
    }
    if (node < n) {
        if (SCALE) {
            float s = dinv[node];
            acc.x *= s; acc.y *= s; acc.z *= s; acc.w *= s;
        }
        *(float4*)&out[(size_t)node * OUTF + of0] = acc;
    }
}

// ---------------- chunked CSR gather on PRE-SCALED rows ----------------
// 8 passes over src chunks; KN nodes/wave-slot in registers; all blocks
// co-resident so passes stay time-correlated -> chunk L2-resident.
template<int F, bool ACT>
__global__ __launch_bounds__(256) void gather_kernel(
        const float* __restrict__ hp, const float* __restrict__ dinv,
        const int* __restrict__ rpc, const int* __restrict__ col,
        const float* __restrict__ bias, float* __restrict__ agg, int n) {
    constexpr int NPW = 64 / F;
    int wid  = (blockIdx.x * 256 + threadIdx.x) >> 6;
    int lane = threadIdx.x & 63;
    int sub  = lane / F;
    int f    = lane % F;
    int node0 = (wid * NPW + sub) * KN;
    float acc[KN];
    int   cur[KN];
#pragma unroll
    for (int k = 0; k < KN; ++k) {
        int nd = node0 + k;
        bool ok = nd < n;
        acc[k] = ok ? hp[(size_t)nd * F + f] : 0.f;   // self loop (pre-scaled)
        cur[k] = ok ? rpc[nd] : 0;
    }
#pragma unroll
    for (int p = 1; p <= NCH; ++p) {
#pragma unroll
        for (int k = 0; k < KN; ++k) {
            int nd = node0 + k;
            if (nd >= n) continue;
            int e  = cur[k];
            int e1 = rpc[(size_t)p * n + nd];
            float t0 = 0.f, t1 = 0.f, t2 = 0.f, t3 = 0.f;
            for (; e + 4 <= e1; e += 4) {
                int c0 = ld_nt_i32(&col[e]);
                int c1 = ld_nt_i32(&col[e + 1]);
                int c2 = ld_nt_i32(&col[e + 2]);
                int c3 = ld_nt_i32(&col[e + 3]);
                t0 += hp[(size_t)c0 * F + f];
                t1 += hp[(size_t)c1 * F + f];
                t2 += hp[(size_t)c2 * F + f];
                t3 += hp[(size_t)c3 * F + f];
            }
            for (; e < e1; ++e) t0 += hp[(size_t)ld_nt_i32(&col[e]) * F + f];
            acc[k] += (t0 + t1) + (t2 + t3);
            cur[k] = e1;
        }
    }
#pragma unroll
    for (int k = 0; k < KN; ++k) {
        int nd = node0 + k;
        if (nd >= n) continue;
        float a = acc[k] * dinv[nd];
        float r = ACT ? fmaxf(a + bias[f], 0.f) : a;
        agg[(size_t)nd * F + f] = r;
    }
}

// ---------------- mean pool ----------------
__global__ __launch_bounds__(256) void pool_kernel(
        const float* __restrict__ h3, const int* __restrict__ batch,
        int n, float* __restrict__ pool) {
    int g = blockIdx.x;
    int lo = 0, hi = n;
    while (lo < hi) { int m = (lo + hi) >> 1; if (batch[m] < g) lo = m + 1; else hi = m; }
    int s = lo;
    hi = n;
    while (lo < hi) { int m = (lo + hi) >> 1; if (batch[m] < g + 1) lo = m + 1; else hi = m; }
    int e = lo;
    constexpr int F = OUT3;
    int ln = threadIdx.x / F;
    int f  = threadIdx.x % F;
    float acc = 0.f;
    for (int i = s + ln; i < e; i += 8)
        acc += h3[(size_t)i * F + f];
    __shared__ float red[8][F];
    red[ln][f] = acc;
    __syncthreads();
    if (ln == 0) {
        float t = 0.f;
#pragma unroll
        for (int j = 0; j < 8; ++j) t += red[j][f];
        float cnt = (float)((e - s) > 0 ? (e - s) : 1);
        pool[g * F + f] = t / cnt;
    }
}

// ---------------- head ----------------
__global__ __launch_bounds__(256) void head_kernel(
        const float* __restrict__ pool, const float* __restrict__ Wh1,
        const float* __restrict__ bh1, const float* __restrict__ Wh2,
        const float* __restrict__ bh2, float* __restrict__ out) {
    __shared__ float sW1[32 * 32];
    __shared__ float sb1[32];
    __shared__ float sW2[32];
    int t = threadIdx.x;
    for (int i = t; i < 1024; i += 256) sW1[i] = Wh1[i];
    if (t < 32) { sb1[t] = bh1[t]; sW2[t] = Wh2[t]; }
    __syncthreads();
    int g = t;
    float y = bh2[0];
    const float* p = &pool[g * 32];
#pragma unroll 4
    for (int j = 0; j < 32; ++j) {
        float a = sb1[j];
#pragma unroll
        for (int k = 0; k < 32; ++k) a += p[k] * sW1[k * 32 + j];
        y += fmaxf(a, 0.f) * sW2[j];
    }
    out[g] = y;
}

extern "C" void kernel_launch(void* const* d_in, const int* in_sizes, int n_in,
                              void* d_out, int out_size, void* d_ws, size_t ws_size,
                              hipStream_t stream) {
    const float* x    = (const float*)d_in[0];
    const int*   ei   = (const int*)  d_in[1];
    const int*   batch= (const int*)  d_in[2];
    const float* W1   = (const float*)d_in[3];
    const float* b1   = (const float*)d_in[4];
    const float* W2   = (const float*)d_in[5];
    const float* b2   = (const float*)d_in[6];
    const float* W3   = (const float*)d_in[7];
    const float* b3   = (const float*)d_in[8];
    const float* Wh1  = (const float*)d_in[9];
    const float* bh1  = (const float*)d_in[10];
    const float* Wh2  = (const float*)d_in[11];
    const float* bh2  = (const float*)d_in[12];
    float* out = (float*)d_out;

    const int N = in_sizes[0] / IN_DIM;
    const int E = in_sizes[1] / 2;
    const int* src = ei;
    const int* dst = ei + E;
    const int NB = (N + BK_NODES - 1) >> BK_LOG;

    // workspace layout (all 4B elements)
    char* base = (char*)d_ws;
    unsigned int* ebuf = (unsigned int*)base;       base += (size_t)E * 4;
    int*   bhist   = (int*)base;                    base += (size_t)MAXB * 4;
    int*   bbase   = (int*)base;                    base += (size_t)(MAXB + 1) * 4;
    int*   cursor  = (int*)base;                    base += (size_t)MAXB * 4;
    int*   rpc     = (int*)base;                    base += (size_t)(NCH + 1) * N * 4;
    float* dinv    = (float*)base;                  base += (size_t)N * 4;
    float* W1p     = (float*)base;                  base += (size_t)32 * HID * 4;
    float* bufA    = (float*)base;                  base += (size_t)N * HID * 4;
    float* bufB    = (float*)base;                  base += (size_t)N * HID * 4;
    float* pool    = (float*)base;

    // ---- CSR build (coalesced counting sort, chunk-grouped rows) ----
    hipMemsetAsync(bhist, 0, (size_t)MAXB * sizeof(int), stream);
    bucket_hist<<<(E + 8191) / 8192, 256, 0, stream>>>(dst, bhist, E);
    bucket_scan<<<1, 256, 0, stream>>>(bhist, bbase, cursor, NB, E);
    partition_kernel<<<(E + EPB1 - 1) / EPB1, 256, 0, stream>>>(src, dst, cursor, ebuf, E);
    bucket_csr_kernel<<<NB, 256, 0, stream>>>(ebuf, bbase, dinv, rpc, N);
    const int* col = (const int*)ebuf;

    const int G64 = (N + KN * 4 - 1) / (KN * 4);        // F=64 grid
    const int G32 = (N + KN * 8 - 1) / (KN * 8);        // F=32 grid

    // ---- layer 1 (reordered): aggX = A_hat Xp' ; h1 = relu(aggX @ W1p + b1)
    padx_kernel<<<((size_t)N * 32 + 255) / 256, 256, 0, stream>>>(x, dinv, bufB, N);
    padw_kernel<<<(32 * HID + 255) / 256, 256, 0, stream>>>(W1, W1p);
    gather_kernel<32, false><<<G32, 256, 0, stream>>>(bufB, dinv, rpc, col, nullptr, bufA, N);
    gemm_kernel<32, HID, true, false><<<(N + 15) / 16, 256, 0, stream>>>(bufA, W1p, b1, nullptr, bufB, N);

    // ---- layer 2: t2' = (h1 @ W2)*dinv ; h2 = relu(dinv*(sum t2') + b2) ----
    gemm_kernel<HID, HID, false, true><<<(N + 15) / 16, 256, 0, stream>>>(bufB, W2, nullptr, dinv, bufA, N);
    gather_kernel<HID, true><<<G64, 256, 0, stream>>>(bufA, dinv, rpc, col, b2, bufB, N);

    // ---- layer 3: t3' = (h2 @ W3)*dinv ; h3 = relu(dinv*(sum t3') + b3) ----
    gemm_kernel<HID, OUT3, false, true><<<(N + 31) / 32, 256, 0, stream>>>(bufB, W3, nullptr, dinv, bufA, N);
    gather_kernel<OUT3, true><<<G32, 256, 0, stream>>>(bufA, dinv, rpc, col, b3, bufB, N);

    // ---- pool + head ----
    pool_kernel<<<256, 256, 0, stream>>>(bufB, batch, N, pool);
    head_kernel<<<1, 256, 0, stream>>>(pool, Wh1, bh1, Wh2, bh2, out);
}

// Round 9
// 630.630 us; speedup vs baseline: 2.1082x; 2.1082x over previous
//
#include <hip/hip_runtime.h>
#include <hip/hip_bf16.h>

// GNN: 3x GCNConv (25->64->64->32) + global mean pool (256 graphs) + MLP head.
// Round 8: R8's register-chunked gather halved FETCH (542->276MB) but
// tripled time (occupancy 35%, ~4-edge segments killed MLP). Revert to the
// R7 flat gather (unroll 16, 4 accs, full occupancy) but KEEP chunk-sorted
// row ordering: rows all have degree ~33, co-resident waves progress in
// near-lockstep through chunks 0..7 -> soft L2 locality at zero cost.
// Partition stage rebuilt without the 96KB LDS staging (was 1 block/CU):
// LDS hist -> per-(block,bucket) global run reservation -> direct run
// writes (runs ~21 contiguous edges => lines mostly single-owner).
// Assumes N <= 131072 (17-bit src packing).

#define IN_DIM 25
#define HID 64
#define OUT3 32
#define BK_LOG 7
#define BK_NODES 128
#define MAXB 1024
#define EPB 16384
#define BCAP 8192
#define NCH 8            // src chunks (chunk = 16384 nodes)
#define NKEY 1024        // 128 dst-low * 8 chunks

__device__ inline int ld_nt_i32(const int* p) {
    return __builtin_nontemporal_load(p);
}

// ---------------- stage 1: bucket histogram (LDS-privatized) ----------------
__global__ __launch_bounds__(256) void bucket_hist(const int* __restrict__ dst,
                                                   int* __restrict__ bhist, int nE) {
    __shared__ int h[MAXB];
    for (int i = threadIdx.x; i < MAXB; i += 256) h[i] = 0;
    __syncthreads();
    int e0 = blockIdx.x * 8192;
    int cnt = min(8192, nE - e0);
    for (int i = threadIdx.x; i < cnt; i += 256)
        atomicAdd(&h[(unsigned)dst[e0 + i] >> BK_LOG], 1);
    __syncthreads();
    for (int i = threadIdx.x; i < MAXB; i += 256)
        if (h[i]) atomicAdd(&bhist[i], h[i]);
}

// ---------------- stage 2: scan bucket counts (1 block) ----------------
__global__ __launch_bounds__(256) void bucket_scan(const int* __restrict__ bhist,
                                                   int* __restrict__ bbase,
                                                   int* __restrict__ cursor,
                                                   int* __restrict__ row_ptr,
                                                   int nb, int nE, int nN) {
    __shared__ int s4[256];
    int t = threadIdx.x;
    int v[4]; int sum = 0;
#pragma unroll
    for (int j = 0; j < 4; ++j) {
        int b = 4 * t + j;
        v[j] = (b < nb) ? bhist[b] : 0;
        sum += v[j];
    }
    s4[t] = sum;
    __syncthreads();
    for (int off = 1; off < 256; off <<= 1) {
        int mine = s4[t];
        int add = (t >= off) ? s4[t - off] : 0;
        __syncthreads();
        s4[t] = mine + add;
        __syncthreads();
    }
    int run = s4[t] - sum;
#pragma unroll
    for (int j = 0; j < 4; ++j) {
        int b = 4 * t + j;
        if (b < nb) { bbase[b] = run; cursor[b] = run; }
        run += v[j];
    }
    if (t == 0) { bbase[nb] = nE; row_ptr[nN] = nE; }
}

// ---------------- stage 3: partition into buckets (direct run writes) ------
// LDS hist -> reserve one global run per (block,bucket) -> scatter into the
// run. Runs avg 21 contiguous edges => cache lines mostly single-owner.
__global__ __launch_bounds__(256) void partition_kernel(
        const int* __restrict__ src, const int* __restrict__ dst,
        int* __restrict__ cursor, unsigned int* __restrict__ ebuf, int nE) {
    __shared__ int lh[MAXB];    // hist
    __shared__ int lrun[MAXB];  // global run base
    __shared__ int lcur[MAXB];  // local fill cursor
    int t = threadIdx.x;
    int e0 = blockIdx.x * EPB;
    int cnt = min(EPB, nE - e0);
    for (int i = t; i < MAXB; i += 256) lh[i] = 0;
    __syncthreads();
    for (int i = t; i < cnt; i += 256)
        atomicAdd(&lh[(unsigned)dst[e0 + i] >> BK_LOG], 1);
    __syncthreads();
#pragma unroll
    for (int j = 0; j < 4; ++j) {
        int b = 4 * t + j;
        int v = lh[b];
        lcur[b] = 0;
        if (v > 0) lrun[b] = atomicAdd(&cursor[b], v);
    }
    __syncthreads();
    for (int i = t; i < cnt; i += 256) {
        int d = dst[e0 + i];
        int s = src[e0 + i];
        int b = (unsigned)d >> BK_LOG;
        int lp = atomicAdd(&lcur[b], 1);
        ebuf[lrun[b] + lp] = ((unsigned)(d & (BK_NODES - 1)) << 17) | (unsigned)s;
    }
}

// ---------------- stage 4: per-bucket sort by (dst_low, src_chunk) ---------
// key = word >> 14 (7b dst_low + 3b src chunk). Emits row_ptr + dinv;
// rows come out chunk-sorted (soft locality for the flat gather).
__global__ __launch_bounds__(256) void bucket_csr_kernel(
        unsigned int* __restrict__ ebuf, const int* __restrict__ bbase,
        float* __restrict__ dinv, int* __restrict__ row_ptr, int nN) {
    int b = blockIdx.x;
    int node_lo = b << BK_LOG;
    int nn = min(BK_NODES, nN - node_lo);
    int base = bbase[b];
    int cnt = bbase[b + 1] - base;
    if (cnt > BCAP) cnt = BCAP;
    __shared__ unsigned int in[BCAP];    // 32KB
    __shared__ unsigned int outb[BCAP];  // 32KB
    __shared__ int h2[NKEY], sc2[NKEY], lc2[NKEY];   // 12KB
    __shared__ int swp[256];
    int t = threadIdx.x;
    for (int i = t; i < cnt; i += 256) in[i] = ebuf[base + i];
    for (int i = t; i < NKEY; i += 256) { h2[i] = 0; lc2[i] = 0; }
    __syncthreads();
    for (int i = t; i < cnt; i += 256) atomicAdd(&h2[in[i] >> 14], 1);
    __syncthreads();
    int v[4]; int sum = 0;
#pragma unroll
    for (int j = 0; j < 4; ++j) { v[j] = h2[4 * t + j]; sum += v[j]; }
    swp[t] = sum;
    __syncthreads();
    for (int off = 1; off < 256; off <<= 1) {
        int mine = swp[t];
        int add = (t >= off) ? swp[t - off] : 0;
        __syncthreads();
        swp[t] = mine + add;
        __syncthreads();
    }
    int run = swp[t] - sum;
#pragma unroll
    for (int j = 0; j < 4; ++j) {
        run += v[j];
        sc2[4 * t + j] = run;     // inclusive scan
    }
    __syncthreads();
    // row_ptr + dinv: node t spans keys [t*8, t*8+8)
    if (t < BK_NODES && t < nn) {
        int k0 = t * NCH;
        int eStart = sc2[k0] - h2[k0];
        int eEnd = (k0 + NCH < NKEY) ? (sc2[k0 + NCH] - h2[k0 + NCH]) : cnt;
        row_ptr[node_lo + t] = base + eStart;
        dinv[node_lo + t] = rsqrtf((float)(eEnd - eStart) + 1.0f);
    }
    __syncthreads();
    for (int i = t; i < cnt; i += 256) {
        unsigned int w = in[i];
        int key = w >> 14;
        int lp = atomicAdd(&lc2[key], 1);
        outb[(sc2[key] - h2[key]) + lp] = w & 0x1FFFFu;
    }
    __syncthreads();
    for (int i = t; i < cnt; i += 256) ebuf[base + i] = outb[i];
}

// ---------------- pad + pre-scale helpers ----------------
__global__ void padx_kernel(const float* __restrict__ x, const float* __restrict__ dinv,
                            float* __restrict__ xp, int n) {
    int i = blockIdx.x * 256 + threadIdx.x;
    if (i < n * 32) {
        int node = i >> 5, c = i & 31;
        xp[i] = (c < IN_DIM) ? x[(size_t)node * IN_DIM + c] * dinv[node] : 0.f;
    }
}

__global__ void padw_kernel(const float* __restrict__ W1, float* __restrict__ W1p) {
    int i = blockIdx.x * 256 + threadIdx.x;
    if (i < 32 * HID) {
        int r = i >> 6, c = i & 63;
        W1p[i] = (r < IN_DIM) ? W1[r * HID + c] : 0.f;
    }
}

// ---------------- dense layer: out = in @ W [*dinv] [+bias,relu] -----------
template<int INF, int OUTF, bool ACT, bool SCALE>
__global__ __launch_bounds__(256) void gemm_kernel(
        const float* __restrict__ in, const float* __restrict__ W,
        const float* __restrict__ bias, const float* __restrict__ dinv,
        float* __restrict__ out, int n) {
    constexpr int TPN = OUTF / 4;
    constexpr int NPB = 256 / TPN;
    constexpr int LDK = INF + 4;
    __shared__ float sW[INF * OUTF];
    __shared__ float sIn[NPB][LDK];
    for (int i = threadIdx.x; i < INF * OUTF; i += 256) sW[i] = W[i];
    int node0 = blockIdx.x * NPB;
    for (int i = threadIdx.x; i < NPB * INF; i += 256) {
        int ln = i / INF, k = i % INF;
        int node = node0 + ln;
        sIn[ln][k] = (node < n) ? in[(size_t)node * INF + k] : 0.f;
    }
    __syncthreads();
    int g   = threadIdx.x / TPN;
    int of0 = (threadIdx.x % TPN) * 4;
    int node = node0 + g;
    float4 acc = make_float4(0.f, 0.f, 0.f, 0.f);
#pragma unroll
    for (int k = 0; k < INF; ++k) {
        float aj = sIn[g][k];
        const float4 wv = *(const float4*)&sW[k * OUTF + of0];
        acc.x += aj * wv.x; acc.y += aj * wv.y;
        acc.z += aj * wv.z; acc.w += aj * wv.w;
    }
    if (ACT) {
        const float4 bv = *(const float4*)&bias[of0];
        acc.x = fmaxf(acc.x + bv.x, 0.f);
        acc.y = fmaxf(acc.y + bv.y, 0.f);
        acc.z = fmaxf(acc.z + bv.z, 0.f);
        acc.w = fmaxf(acc.w + bv.w, 0.f);
    }
    if (node < n) {
        if (SCALE) {
            float s = dinv[node];
            acc.x *= s; acc.y *= s; acc.z *= s; acc.w *= s;
        }
        *(float4*)&out[(size_t)node * OUTF + of0] = acc;
    }
}

// ---------------- flat CSR gather on PRE-SCALED rows (chunk-sorted rows) ----
template<int F, bool ACT>
__global__ __launch_bounds__(256) void gather_kernel(
        const float* __restrict__ hp, const float* __restrict__ dinv,
        const int* __restrict__ row_ptr, const int* __restrict__ col,
        const float* __restrict__ bias, float* __restrict__ agg, int n) {
    constexpr int NPW = 64 / F;
    int wid  = (blockIdx.x * 256 + threadIdx.x) >> 6;
    int lane = threadIdx.x & 63;
    int sub  = lane / F;
    int f    = lane % F;
    int node = wid * NPW + sub;
    if (node >= n) return;
    float a0 = hp[(size_t)node * F + f];   // self loop (pre-scaled)
    float a1 = 0.f, a2 = 0.f, a3 = 0.f;
    int e = row_ptr[node], end = row_ptr[node + 1];
    for (; e + 16 <= end; e += 16) {
        int c[16];
#pragma unroll
        for (int j = 0; j < 16; ++j) c[j] = ld_nt_i32(&col[e + j]);
        float v[16];
#pragma unroll
        for (int j = 0; j < 16; ++j) v[j] = hp[(size_t)c[j] * F + f];
#pragma unroll
        for (int j = 0; j < 4; ++j) {
            a0 += v[4 * j];     a1 += v[4 * j + 1];
            a2 += v[4 * j + 2]; a3 += v[4 * j + 3];
        }
    }
    for (; e + 4 <= end; e += 4) {
        int c0 = ld_nt_i32(&col[e]),     c1 = ld_nt_i32(&col[e + 1]);
        int c2 = ld_nt_i32(&col[e + 2]), c3 = ld_nt_i32(&col[e + 3]);
        a0 += hp[(size_t)c0 * F + f]; a1 += hp[(size_t)c1 * F + f];
        a2 += hp[(size_t)c2 * F + f]; a3 += hp[(size_t)c3 * F + f];
    }
    for (; e < end; ++e) a0 += hp[(size_t)ld_nt_i32(&col[e]) * F + f];
    float acc = ((a0 + a1) + (a2 + a3)) * dinv[node];
    float r = ACT ? fmaxf(acc + bias[f], 0.f) : acc;
    agg[(size_t)node * F + f] = r;
}

// ---------------- mean pool ----------------
__global__ __launch_bounds__(256) void pool_kernel(
        const float* __restrict__ h3, const int* __restrict__ batch,
        int n, float* __restrict__ pool) {
    int g = blockIdx.x;
    int lo = 0, hi = n;
    while (lo < hi) { int m = (lo + hi) >> 1; if (batch[m] < g) lo = m + 1; else hi = m; }
    int s = lo;
    hi = n;
    while (lo < hi) { int m = (lo + hi) >> 1; if (batch[m] < g + 1) lo = m + 1; else hi = m; }
    int e = lo;
    constexpr int F = OUT3;
    int ln = threadIdx.x / F;
    int f  = threadIdx.x % F;
    float acc = 0.f;
    for (int i = s + ln; i < e; i += 8)
        acc += h3[(size_t)i * F + f];
    __shared__ float red[8][F];
    red[ln][f] = acc;
    __syncthreads();
    if (ln == 0) {
        float t = 0.f;
#pragma unroll
        for (int j = 0; j < 8; ++j) t += red[j][f];
        float cnt = (float)((e - s) > 0 ? (e - s) : 1);
        pool[g * F + f] = t / cnt;
    }
}

// ---------------- head ----------------
__global__ __launch_bounds__(256) void head_kernel(
        const float* __restrict__ pool, const float* __restrict__ Wh1,
        const float* __restrict__ bh1, const float* __restrict__ Wh2,
        const float* __restrict__ bh2, float* __restrict__ out) {
    __shared__ float sW1[32 * 32];
    __shared__ float sb1[32];
    __shared__ float sW2[32];
    int t = threadIdx.x;
    for (int i = t; i < 1024; i += 256) sW1[i] = Wh1[i];
    if (t < 32) { sb1[t] = bh1[t]; sW2[t] = Wh2[t]; }
    __syncthreads();
    int g = t;
    float y = bh2[0];
    const float* p = &pool[g * 32];
#pragma unroll 4
    for (int j = 0; j < 32; ++j) {
        float a = sb1[j];
#pragma unroll
        for (int k = 0; k < 32; ++k) a += p[k] * sW1[k * 32 + j];
        y += fmaxf(a, 0.f) * sW2[j];
    }
    out[g] = y;
}

extern "C" void kernel_launch(void* const* d_in, const int* in_sizes, int n_in,
                              void* d_out, int out_size, void* d_ws, size_t ws_size,
                              hipStream_t stream) {
    const float* x    = (const float*)d_in[0];
    const int*   ei   = (const int*)  d_in[1];
    const int*   batch= (const int*)  d_in[2];
    const float* W1   = (const float*)d_in[3];
    const float* b1   = (const float*)d_in[4];
    const float* W2   = (const float*)d_in[5];
    const float* b2   = (const float*)d_in[6];
    const float* W3   = (const float*)d_in[7];
    const float* b3   = (const float*)d_in[8];
    const float* Wh1  = (const float*)d_in[9];
    const float* bh1  = (const float*)d_in[10];
    const float* Wh2  = (const float*)d_in[11];
    const float* bh2  = (const float*)d_in[12];
    float* out = (float*)d_out;

    const int N = in_sizes[0] / IN_DIM;
    const int E = in_sizes[1] / 2;
    const int* src = ei;
    const int* dst = ei + E;
    const int NB = (N + BK_NODES - 1) >> BK_LOG;

    // workspace layout (all 4B elements)
    char* base = (char*)d_ws;
    unsigned int* ebuf = (unsigned int*)base;       base += (size_t)E * 4;
    int*   bhist   = (int*)base;                    base += (size_t)MAXB * 4;
    int*   bbase   = (int*)base;                    base += (size_t)(MAXB + 1) * 4;
    int*   cursor  = (int*)base;                    base += (size_t)MAXB * 4;
    int*   row_ptr = (int*)base;                    base += (size_t)(N + 1) * 4;
    float* dinv    = (float*)base;                  base += (size_t)N * 4;
    float* W1p     = (float*)base;                  base += (size_t)32 * HID * 4;
    float* bufA    = (float*)base;                  base += (size_t)N * HID * 4;
    float* bufB    = (float*)base;                  base += (size_t)N * HID * 4;
    float* pool    = (float*)base;

    // ---- CSR build ----
    hipMemsetAsync(bhist, 0, (size_t)MAXB * sizeof(int), stream);
    bucket_hist<<<(E + 8191) / 8192, 256, 0, stream>>>(dst, bhist, E);
    bucket_scan<<<1, 256, 0, stream>>>(bhist, bbase, cursor, row_ptr, NB, E, N);
    partition_kernel<<<(E + EPB - 1) / EPB, 256, 0, stream>>>(src, dst, cursor, ebuf, E);
    bucket_csr_kernel<<<NB, 256, 0, stream>>>(ebuf, bbase, dinv, row_ptr, N);
    const int* col = (const int*)ebuf;

    // ---- layer 1 (reordered): aggX = A_hat Xp' ; h1 = relu(aggX @ W1p + b1)
    padx_kernel<<<((size_t)N * 32 + 255) / 256, 256, 0, stream>>>(x, dinv, bufB, N);
    padw_kernel<<<(32 * HID + 255) / 256, 256, 0, stream>>>(W1, W1p);
    gather_kernel<32, false><<<(N + 7) / 8, 256, 0, stream>>>(bufB, dinv, row_ptr, col, nullptr, bufA, N);
    gemm_kernel<32, HID, true, false><<<(N + 15) / 16, 256, 0, stream>>>(bufA, W1p, b1, nullptr, bufB, N);

    // ---- layer 2: t2' = (h1 @ W2)*dinv ; h2 = relu(dinv*(sum t2') + b2) ----
    gemm_kernel<HID, HID, false, true><<<(N + 15) / 16, 256, 0, stream>>>(bufB, W2, nullptr, dinv, bufA, N);
    gather_kernel<HID, true><<<(N + 3) / 4, 256, 0, stream>>>(bufA, dinv, row_ptr, col, b2, bufB, N);

    // ---- layer 3: t3' = (h2 @ W3)*dinv ; h3 = relu(dinv*(sum t3') + b3) ----
    gemm_kernel<HID, OUT3, false, true><<<(N + 31) / 32, 256, 0, stream>>>(bufB, W3, nullptr, dinv, bufA, N);
    gather_kernel<OUT3, true><<<(N + 7) / 8, 256, 0, stream>>>(bufA, dinv, row_ptr, col, b3, bufB, N);

    // ---- pool + head ----
    pool_kernel<<<256, 256, 0, stream>>>(bufB, batch, N, pool);
    head_kernel<<<1, 256, 0, stream>>>(pool, Wh1, bh1, Wh2, bh2, out);
}